// Round 8
// baseline (38.895 us; speedup 1.0000x reference)
//
#include <hip/hip_runtime.h>
#include <math.h>

#define BATCH 256
#define CIN   3
#define COUT  16
#define DI    16
#define HI    32
#define WI    32

typedef _Float16 f16;
typedef f16   f16x4 __attribute__((ext_vector_type(4)));
typedef f16   f16x8 __attribute__((ext_vector_type(8)));
typedef float f32x4 __attribute__((ext_vector_type(4)));

// LDS slab (f16 units): xs[dd][hh][wslot][ci]; 18 w-slots per row (w-split!),
// ci stride 1 (3 cin + zero pad), row stride RS=72 f16 (144B), plane 30 rows.
// 144B row ≡ 16 mod 128 -> B-read lanes spread over banks, <=2-way (free).
#define RS     72
#define PLANE  2160
#define XS_N   (6 * PLANE)          // 12960 f16 = 25920 B -> 6 WG/CU
#define G8OFF  (2 * PLANE + 2 * RS) // (kd=2,kh=2) row offset = 4464

#define SV8(a, b) __builtin_shufflevector(a, b, 0, 1, 2, 3, 4, 5, 6, 7)
#define MFMA16(A, B, C) __builtin_amdgcn_mfma_f32_16x16x32_f16(A, B, C, 0, 0, 0)

// max-reduce over the 16-lane col group on the VALU pipe (DPP row_ror),
// replacing 4 LDS-pipe swizzles per register. Exact for max.
#define DPPMAX(v, ctrl) do {                                                  \
    int t_ = __builtin_amdgcn_update_dpp(                                     \
        0, __builtin_bit_cast(int, v), (ctrl), 0xF, 0xF, false);              \
    v = fmaxf(v, __builtin_bit_cast(float, t_));                              \
} while (0)

// One (cell,d) step: 8 ds_read_b64 + 4-chain MFMA + softmax + pool accumulate.
#define CELLD(rb, pmv)  do {                                                  \
    const f16* rb_ = (rb);                                                    \
    f16x4 b10_ = *(const f16x4*)(rb_ + off1);                                 \
    f16x4 b20_ = *(const f16x4*)(rb_ + off2);                                 \
    f16x4 b11_ = *(const f16x4*)(rb_ + off1 + 4);                             \
    f16x4 b21_ = *(const f16x4*)(rb_ + off2 + 4);                             \
    f16x4 b12_ = *(const f16x4*)(rb_ + off1 + 8);                             \
    f16x4 b22_ = *(const f16x4*)(rb_ + off2 + 8);                             \
    f16x4 ga_  = *(const f16x4*)(rb_ + G8OFF + g8sel);                        \
    f16x4 gb_  = *(const f16x4*)(rb_ + G8OFF + 4);                            \
    f32x4 a_ = {0.f, 0.f, 0.f, 0.f};                                          \
    a_ = MFMA16(wm[0], SV8(b10_, b20_), a_);                                  \
    a_ = MFMA16(wm[1], SV8(b11_, b21_), a_);                                  \
    a_ = MFMA16(wm[2], SV8(b12_, b22_), a_);                                  \
    a_ = MFMA16(wg,    SV8(ga_,  gb_),  a_);                                  \
    float y0_ = a_[0] + bv.x, y1_ = a_[1] + bv.y;                             \
    float y2_ = a_[2] + bv.z, y3_ = a_[3] + bv.w;                             \
    float e0_ = __expf(y0_), e1_ = __expf(y1_);                               \
    float e2_ = __expf(y2_), e3_ = __expf(y3_);                               \
    float s_ = (e0_ + e1_) + (e2_ + e3_);                                     \
    s_ += __shfl_xor(s_, 16);                                                 \
    s_ += __shfl_xor(s_, 32);                                                 \
    float inv_ = __builtin_amdgcn_rcpf(s_);                                   \
    pmv[0] = fmaxf(pmv[0], e0_ * inv_);                                       \
    pmv[1] = fmaxf(pmv[1], e1_ * inv_);                                       \
    pmv[2] = fmaxf(pmv[2], e2_ * inv_);                                       \
    pmv[3] = fmaxf(pmv[3], e3_ * inv_);                                       \
} while (0)

// ---------------------------------------------------------------------------
// Fused conv3d + bias + channel-softmax + 4^3 maxpool.
// Grid 1536: one WG per (b, pd, w-chunk). Chunk 0: pw 0..3 (w slots 0..17),
// chunk 1: pw 4..6 (w slots 16..29 stored rebased). 25.9 KB LDS -> 6 WG/CU,
// 24 waves/CU. Pool over cell positions on VALU via DPP row_ror.
// ---------------------------------------------------------------------------
__global__ __launch_bounds__(256, 8) void conv_sm_pool_mfma(
    const float* __restrict__ x, const float* __restrict__ W,
    const float* __restrict__ bias, float* __restrict__ out)
{
    __shared__ __align__(16) f16 xs[XS_N];

    const int tid  = threadIdx.x;
    const int lane = tid & 63;
    const int wave = tid >> 6;
    const int bid  = blockIdx.x;
    const int cw   = bid & 1;
    const int bp   = bid >> 1;
    const int b    = bp / 3;
    const int pd   = bp % 3;
    const int d0   = pd * 4;

    const int col = lane & 15;     // MFMA column = position in cell (hl*4+wl)
    const int kq  = lane >> 4;     // K-slot group

    // ---- W gather -> A-fragments (k = g*4 + ci, g = kd*3+kh; groups 2kq,2kq+1) ----
    const float* wc  = W + col * 81;
    const float* wqp = wc + kq * 6;
    f16x8 wm[3];
    #pragma unroll
    for (int kw = 0; kw < 3; ++kw) {
        #pragma unroll
        for (int j = 0; j < 8; ++j) {
            const int ci = j & 3, jj = j >> 2;
            float v = (ci < 3) ? wqp[ci * 27 + 3 * jj + kw] : 0.f;
            wm[kw][j] = (f16)v;
        }
    }
    f16x8 wg = {};
    if (kq == 0) {
        #pragma unroll
        for (int j = 0; j < 8; ++j) {
            const int ci = j & 3, kw = j >> 2;
            if (ci < 3) wg[j] = (f16)wc[ci * 27 + 24 + kw];
        }
    } else if (kq == 1) {
        #pragma unroll
        for (int j = 0; j < 3; ++j) wg[j] = (f16)wc[j * 27 + 26];
    }
    const float4 bv = *(const float4*)(bias + kq * 4);   // couts 4kq+0..3

    // ---- Stage this chunk's w-range of x[b,:,d0..d0+5,:] -> f16 LDS ----
    if (cw == 0) {
        // w floats 0..19 -> slots 0..17 (q==4 stores only 2 slots)
        for (int i = tid; i < 900; i += 256) {            // 180 rows * 5 q
            int q = i % 5, r = i / 5;
            int hh = r % 30, dd = r / 30;
            const float* px = x + ((size_t)b * 48 + (d0 + dd)) * 1024 + hh * 32 + q * 4;
            float4 a0 = *(const float4*)(px);
            float4 a1 = *(const float4*)(px + 16384);
            float4 a2 = *(const float4*)(px + 32768);
            f16x8 p0, p1;
            p0[0] = (f16)a0.x; p0[1] = (f16)a1.x; p0[2] = (f16)a2.x; p0[3] = (f16)0.f;
            p0[4] = (f16)a0.y; p0[5] = (f16)a1.y; p0[6] = (f16)a2.y; p0[7] = (f16)0.f;
            p1[0] = (f16)a0.z; p1[1] = (f16)a1.z; p1[2] = (f16)a2.z; p1[3] = (f16)0.f;
            p1[4] = (f16)a0.w; p1[5] = (f16)a1.w; p1[6] = (f16)a2.w; p1[7] = (f16)0.f;
            f16* dst = xs + ((dd * 30 + hh) * 18 + q * 4) * 4;
            *(f16x8*)(dst) = p0;
            if (q < 4) *(f16x8*)(dst + 8) = p1;
        }
    } else {
        // w floats 16..31 -> slots 0..15 (slots 14,15 unused, 16,17 unwritten/unread)
        for (int i = tid; i < 720; i += 256) {            // 180 rows * 4 q
            int q = i & 3, r = i >> 2;
            int hh = r % 30, dd = r / 30;
            const float* px = x + ((size_t)b * 48 + (d0 + dd)) * 1024 + hh * 32 + 16 + q * 4;
            float4 a0 = *(const float4*)(px);
            float4 a1 = *(const float4*)(px + 16384);
            float4 a2 = *(const float4*)(px + 32768);
            f16x8 p0, p1;
            p0[0] = (f16)a0.x; p0[1] = (f16)a1.x; p0[2] = (f16)a2.x; p0[3] = (f16)0.f;
            p0[4] = (f16)a0.y; p0[5] = (f16)a1.y; p0[6] = (f16)a2.y; p0[7] = (f16)0.f;
            p1[0] = (f16)a0.z; p1[1] = (f16)a1.z; p1[2] = (f16)a2.z; p1[3] = (f16)0.f;
            p1[4] = (f16)a0.w; p1[5] = (f16)a1.w; p1[6] = (f16)a2.w; p1[7] = (f16)0.f;
            f16* dst = xs + ((dd * 30 + hh) * 18 + q * 4) * 4;
            *(f16x8*)(dst)     = p0;
            *(f16x8*)(dst + 8) = p1;
        }
    }

    // per-lane B-read invariants
    const int g0   = kq * 2;
    const int off1 = (g0 / 3) * PLANE + (g0 % 3) * RS;
    const int off2 = ((g0 + 1) / 3) * PLANE + ((g0 + 1) % 3) * RS;
    const int hl = col >> 2, wl = col & 3;
    const int spat  = hl * RS + wl * 4;
    const int g8sel = (kq == 1) ? 8 : 0;

    __syncthreads();   // the only barrier

    const int ncell = cw ? 21 : 28;
    for (int c = wave; c < ncell; c += 4) {
        int ch, pwl;
        if (cw == 0) { ch = c >> 2; pwl = c & 3; }
        else         { ch = c / 3;  pwl = c % 3; }
        const f16* base = xs + ch * 4 * RS + pwl * 16 + spat;

        f32x4 pm = {0.f, 0.f, 0.f, 0.f};
        #pragma unroll
        for (int d = 0; d < 4; ++d) {
            CELLD(base + d * PLANE, pm);
        }

        // pool over the 16 positions of the cell: VALU-pipe DPP row_ror reduce
        #pragma unroll
        for (int r = 0; r < 4; ++r) {
            float v = pm[r];
            DPPMAX(v, 0x128);   // row_ror:8
            DPPMAX(v, 0x124);   // row_ror:4
            DPPMAX(v, 0x122);   // row_ror:2
            DPPMAX(v, 0x121);   // row_ror:1
            pm[r] = v;
        }

        if (col == 0) {
            const int pw = cw ? 4 + pwl : pwl;
            float* po = out + ((size_t)b * COUT + kq * 4) * 147 + pd * 49 + ch * 7 + pw;
            po[0]   = pm[0];
            po[147] = pm[1];
            po[294] = pm[2];
            po[441] = pm[3];
        }
    }
}

extern "C" void kernel_launch(void* const* d_in, const int* in_sizes, int n_in,
                              void* d_out, int out_size, void* d_ws, size_t ws_size,
                              hipStream_t stream) {
    const float* x    = (const float*)d_in[0];
    const float* W    = (const float*)d_in[1];
    const float* bias = (const float*)d_in[2];
    float* out = (float*)d_out;

    conv_sm_pool_mfma<<<BATCH * 3 * 2, 256, 0, stream>>>(x, W, bias, out);
}

// Round 9
// 36.281 us; speedup vs baseline: 1.0721x; 1.0721x over previous
//
#include <hip/hip_runtime.h>
#include <math.h>

#define BATCH 256
#define CIN   3
#define COUT  16
#define DI    16
#define HI    32
#define WI    32

typedef _Float16 f16;
typedef f16   f16x4 __attribute__((ext_vector_type(4)));
typedef f16   f16x8 __attribute__((ext_vector_type(8)));
typedef float f32x4 __attribute__((ext_vector_type(4)));

#define LOG2E 1.44269504088896340736f

// LDS slab (f16 units): xs[dd][hh][wslot][ci]; 18 w-slots per row (w-split),
// ci stride 1 (3 cin + zero pad), row stride RS=72 f16 (144B), plane 30 rows.
#define RS     72
#define PLANE  2160
#define XS_N   (6 * PLANE)          // 25920 B -> LDS allows 6 WG/CU
#define G8OFF  (2 * PLANE + 2 * RS) // (kd=2,kh=2) row offset

#define SV8(a, b) __builtin_shufflevector(a, b, 0, 1, 2, 3, 4, 5, 6, 7)
#define MFMA16(A, B, C) __builtin_amdgcn_mfma_f32_16x16x32_f16(A, B, C, 0, 0, 0)

// VALU-pipe max-reduce over 16-lane col group (DPP row_ror). Exact for max.
#define DPPMAX(v, ctrl) do {                                                  \
    int t_ = __builtin_amdgcn_update_dpp(                                     \
        0, __builtin_bit_cast(int, v), (ctrl), 0xF, 0xF, false);              \
    v = fmaxf(v, __builtin_bit_cast(float, t_));                              \
} while (0)

// ---------------------------------------------------------------------------
// Fused conv3d + bias + channel-softmax + 4^3 maxpool.
// Grid 1536: one WG per (b, pd, w-chunk); pair-to-XCD swizzle keeps both
// chunks of a (b,pd) on one XCD's L2. Per cell: ALL 32 B-fragments loaded
// first (sched_group_barrier-pinned), 16 MFMAs as 4 independent chains,
// batched exp2 softmax (weights pre-scaled by log2e), batched shuffles.
// ---------------------------------------------------------------------------
__global__ __launch_bounds__(256, 4) void conv_sm_pool_mfma(
    const float* __restrict__ x, const float* __restrict__ W,
    const float* __restrict__ bias, float* __restrict__ out)
{
    __shared__ __align__(16) f16 xs[XS_N];

    const int tid  = threadIdx.x;
    const int lane = tid & 63;
    const int wave = tid >> 6;

    // wgid = 16*q + 8*cw + (p&7): both chunks of pair p share XCD (hw: %8)
    const int wgid = blockIdx.x;
    const int r8 = wgid & 7;
    const int cw = (wgid >> 3) & 1;
    const int p  = ((wgid >> 4) << 3) + r8;   // pair id 0..767
    const int b  = p / 3;
    const int pd = p % 3;
    const int d0 = pd * 4;

    const int col = lane & 15;     // MFMA column = position in cell (hl*4+wl)
    const int kq  = lane >> 4;     // K-slot group

    // ---- W gather -> A-fragments, PRE-SCALED by log2e (exp -> exp2) ----
    const float* wc  = W + col * 81;
    const float* wqp = wc + kq * 6;
    f16x8 wm[3];
    #pragma unroll
    for (int kw = 0; kw < 3; ++kw) {
        #pragma unroll
        for (int j = 0; j < 8; ++j) {
            const int ci = j & 3, jj = j >> 2;
            float v = (ci < 3) ? wqp[ci * 27 + 3 * jj + kw] * LOG2E : 0.f;
            wm[kw][j] = (f16)v;
        }
    }
    f16x8 wg = {};
    if (kq == 0) {
        #pragma unroll
        for (int j = 0; j < 8; ++j) {
            const int ci = j & 3, kw = j >> 2;
            if (ci < 3) wg[j] = (f16)(wc[ci * 27 + 24 + kw] * LOG2E);
        }
    } else if (kq == 1) {
        #pragma unroll
        for (int j = 0; j < 3; ++j) wg[j] = (f16)(wc[j * 27 + 26] * LOG2E);
    }
    const float4 braw = *(const float4*)(bias + kq * 4);
    float4 bv;
    bv.x = braw.x * LOG2E; bv.y = braw.y * LOG2E;
    bv.z = braw.z * LOG2E; bv.w = braw.w * LOG2E;

    // ---- Stage this chunk's w-range of x[b,:,d0..d0+5,:] -> f16 LDS ----
    if (cw == 0) {
        // w floats 0..19 -> slots 0..17
        for (int i = tid; i < 900; i += 256) {            // 180 rows * 5 q
            int q = i % 5, r = i / 5;
            int hh = r % 30, dd = r / 30;
            const float* px = x + ((size_t)b * 48 + (d0 + dd)) * 1024 + hh * 32 + q * 4;
            float4 a0 = *(const float4*)(px);
            float4 a1 = *(const float4*)(px + 16384);
            float4 a2 = *(const float4*)(px + 32768);
            f16x8 p0, p1;
            p0[0] = (f16)a0.x; p0[1] = (f16)a1.x; p0[2] = (f16)a2.x; p0[3] = (f16)0.f;
            p0[4] = (f16)a0.y; p0[5] = (f16)a1.y; p0[6] = (f16)a2.y; p0[7] = (f16)0.f;
            p1[0] = (f16)a0.z; p1[1] = (f16)a1.z; p1[2] = (f16)a2.z; p1[3] = (f16)0.f;
            p1[4] = (f16)a0.w; p1[5] = (f16)a1.w; p1[6] = (f16)a2.w; p1[7] = (f16)0.f;
            f16* dst = xs + ((dd * 30 + hh) * 18 + q * 4) * 4;
            *(f16x8*)(dst) = p0;
            if (q < 4) *(f16x8*)(dst + 8) = p1;
        }
    } else {
        // w floats 16..31 -> slots 0..15
        for (int i = tid; i < 720; i += 256) {            // 180 rows * 4 q
            int q = i & 3, r = i >> 2;
            int hh = r % 30, dd = r / 30;
            const float* px = x + ((size_t)b * 48 + (d0 + dd)) * 1024 + hh * 32 + 16 + q * 4;
            float4 a0 = *(const float4*)(px);
            float4 a1 = *(const float4*)(px + 16384);
            float4 a2 = *(const float4*)(px + 32768);
            f16x8 p0, p1;
            p0[0] = (f16)a0.x; p0[1] = (f16)a1.x; p0[2] = (f16)a2.x; p0[3] = (f16)0.f;
            p0[4] = (f16)a0.y; p0[5] = (f16)a1.y; p0[6] = (f16)a2.y; p0[7] = (f16)0.f;
            p1[0] = (f16)a0.z; p1[1] = (f16)a1.z; p1[2] = (f16)a2.z; p1[3] = (f16)0.f;
            p1[4] = (f16)a0.w; p1[5] = (f16)a1.w; p1[6] = (f16)a2.w; p1[7] = (f16)0.f;
            f16* dst = xs + ((dd * 30 + hh) * 18 + q * 4) * 4;
            *(f16x8*)(dst)     = p0;
            *(f16x8*)(dst + 8) = p1;
        }
    }

    // per-lane B-read invariants
    const int g0   = kq * 2;
    const int off1 = (g0 / 3) * PLANE + (g0 % 3) * RS;
    const int off2 = ((g0 + 1) / 3) * PLANE + ((g0 + 1) % 3) * RS;
    const int hl = col >> 2, wl = col & 3;
    const int spat  = hl * RS + wl * 4;
    const int g8sel = (kq == 1) ? 8 : 0;

    __syncthreads();   // the only barrier

    const int ncell = cw ? 21 : 28;
    for (int c = wave; c < ncell; c += 4) {
        int ch, pwl;
        if (cw == 0) { ch = c >> 2; pwl = c & 3; }
        else         { ch = c / 3;  pwl = c % 3; }
        const f16* base = xs + ch * 4 * RS + pwl * 16 + spat;
        const f16* a1 = base + off1;
        const f16* a2 = base + off2;
        const f16* a3 = base + G8OFF + g8sel;

        // ---- 32 independent ds_read_b64 (imm offsets off 3 base addrs) ----
        f16x4 Bv[4][8];
        #pragma unroll
        for (int d = 0; d < 4; ++d) {
            const int dp = d * PLANE;
            Bv[d][0] = *(const f16x4*)(a1 + dp);
            Bv[d][1] = *(const f16x4*)(a2 + dp);
            Bv[d][2] = *(const f16x4*)(a1 + dp + 4);
            Bv[d][3] = *(const f16x4*)(a2 + dp + 4);
            Bv[d][4] = *(const f16x4*)(a1 + dp + 8);
            Bv[d][5] = *(const f16x4*)(a2 + dp + 8);
            Bv[d][6] = *(const f16x4*)(a3 + dp);
            Bv[d][7] = *(const f16x4*)(a3 + dp + 4);
        }

        // ---- 16 MFMAs: 4 independent chains of 4 ----
        f32x4 acc[4];
        #pragma unroll
        for (int d = 0; d < 4; ++d) {
            f32x4 a_ = {0.f, 0.f, 0.f, 0.f};
            a_ = MFMA16(wm[0], SV8(Bv[d][0], Bv[d][1]), a_);
            a_ = MFMA16(wm[1], SV8(Bv[d][2], Bv[d][3]), a_);
            a_ = MFMA16(wm[2], SV8(Bv[d][4], Bv[d][5]), a_);
            a_ = MFMA16(wg,    SV8(Bv[d][6], Bv[d][7]), a_);
            acc[d] = a_;
        }
        // pin schedule: all 32 DS reads first, then the 16 MFMAs
        __builtin_amdgcn_sched_group_barrier(0x100, 32, 0);  // DS_READ x32
        __builtin_amdgcn_sched_group_barrier(0x008, 16, 0);  // MFMA x16

        // ---- batched softmax (exp2; weights prescaled) ----
        float ev[4][4], s[4];
        #pragma unroll
        for (int d = 0; d < 4; ++d) {
            float y0 = acc[d][0] + bv.x, y1 = acc[d][1] + bv.y;
            float y2 = acc[d][2] + bv.z, y3 = acc[d][3] + bv.w;
            ev[d][0] = __builtin_amdgcn_exp2f(y0);
            ev[d][1] = __builtin_amdgcn_exp2f(y1);
            ev[d][2] = __builtin_amdgcn_exp2f(y2);
            ev[d][3] = __builtin_amdgcn_exp2f(y3);
            s[d] = (ev[d][0] + ev[d][1]) + (ev[d][2] + ev[d][3]);
        }
        #pragma unroll
        for (int d = 0; d < 4; ++d) s[d] += __shfl_xor(s[d], 16);
        #pragma unroll
        for (int d = 0; d < 4; ++d) s[d] += __shfl_xor(s[d], 32);

        f32x4 pm = {0.f, 0.f, 0.f, 0.f};
        #pragma unroll
        for (int d = 0; d < 4; ++d) {
            float iv = __builtin_amdgcn_rcpf(s[d]);
            pm[0] = fmaxf(pm[0], ev[d][0] * iv);
            pm[1] = fmaxf(pm[1], ev[d][1] * iv);
            pm[2] = fmaxf(pm[2], ev[d][2] * iv);
            pm[3] = fmaxf(pm[3], ev[d][3] * iv);
        }

        // ---- pool over the 16 cell positions on the VALU pipe ----
        #pragma unroll
        for (int r = 0; r < 4; ++r) {
            float v = pm[r];
            DPPMAX(v, 0x128);   // row_ror:8
            DPPMAX(v, 0x124);   // row_ror:4
            DPPMAX(v, 0x122);   // row_ror:2
            DPPMAX(v, 0x121);   // row_ror:1
            pm[r] = v;
        }

        if (col == 0) {
            const int pw = cw ? 4 + pwl : pwl;
            float* po = out + ((size_t)b * COUT + kq * 4) * 147 + pd * 49 + ch * 7 + pw;
            po[0]   = pm[0];
            po[147] = pm[1];
            po[294] = pm[2];
            po[441] = pm[3];
        }
    }
}

extern "C" void kernel_launch(void* const* d_in, const int* in_sizes, int n_in,
                              void* d_out, int out_size, void* d_ws, size_t ws_size,
                              hipStream_t stream) {
    const float* x    = (const float*)d_in[0];
    const float* W    = (const float*)d_in[1];
    const float* bias = (const float*)d_in[2];
    float* out = (float*)d_out;

    conv_sm_pool_mfma<<<BATCH * 3 * 2, 256, 0, stream>>>(x, W, bias, out);
}

// Round 10
// 30.412 us; speedup vs baseline: 1.2790x; 1.1930x over previous
//
#include <hip/hip_runtime.h>
#include <math.h>

#define BATCH 256
#define CIN   3
#define COUT  16
#define DI    16
#define HI    32
#define WI    32

typedef _Float16 f16;
typedef f16   f16x4 __attribute__((ext_vector_type(4)));
typedef f16   f16x8 __attribute__((ext_vector_type(8)));
typedef float f32x4 __attribute__((ext_vector_type(4)));

#define LOG2E 1.44269504088896340736f

// LDS slab (f16 units): xs[dd][hh][w][ci], ci stride 1 (3 cin + zero pad),
// w stride 4, row stride ROWU=144 f16 (288B), plane stride PLANEU=4320.
// 288B ≡ 32 mod 128 -> 16-col lane group covers all 32 banks; kq-group
// offsets {0,64,96,0} mod 128 -> <=2-way aliasing (free). [R5: 737K conflicts]
#define ROWU   144
#define PLANEU 4320
#define XS_N   (6 * PLANEU)              // 51840 B -> 3 WG/CU (24 waves/CU @512thr)
#define G8OFF  (2 * PLANEU + 2 * ROWU)   // (kd=2,kh=2) row offset

#define SV8(a, b) __builtin_shufflevector(a, b, 0, 1, 2, 3, 4, 5, 6, 7)
#define MFMA16(A, B, C) __builtin_amdgcn_mfma_f32_16x16x32_f16(A, B, C, 0, 0, 0)

// VALU-pipe max-reduce over the 16-lane col group (DPP row_ror). Exact for max.
#define DPPMAX(v, ctrl) do {                                                  \
    int t_ = __builtin_amdgcn_update_dpp(                                     \
        0, __builtin_bit_cast(int, v), (ctrl), 0xF, 0xF, false);              \
    v = fmaxf(v, __builtin_bit_cast(float, t_));                              \
} while (0)

// ---------------------------------------------------------------------------
// Fused conv3d + bias + channel-softmax + 4^3 maxpool.
// One 512-thread WG (8 waves) per (b,pd); 768 WGs = 3 WG/CU, whole grid
// resident, ONE barrier. Each wave owns complete pool cells (~6 each).
// R5's conflict-free LDS layout + exp2-prescaled weights + DPP pool.
// ---------------------------------------------------------------------------
__global__ __launch_bounds__(512, 6) void conv_sm_pool_mfma(
    const float* __restrict__ x, const float* __restrict__ W,
    const float* __restrict__ bias, float* __restrict__ out)
{
    __shared__ __align__(16) f16 xs[XS_N];

    const int tid  = threadIdx.x;
    const int lane = tid & 63;
    const int wave = tid >> 6;           // 0..7
    const int b    = blockIdx.x / 3;
    const int pd   = blockIdx.x % 3;
    const int d0   = pd * 4;

    const int col = lane & 15;     // MFMA column = position in cell (hl*4+wl)
    const int kq  = lane >> 4;     // K-slot group

    // ---- W gather -> A-fragments, PRE-SCALED by log2e (exp -> exp2) ----
    // k = g*4 + ci, g = kd*3+kh; this lane holds groups 2kq, 2kq+1.
    const float* wc  = W + col * 81;
    const float* wqp = wc + kq * 6;
    f16x8 wm[3];
    #pragma unroll
    for (int kw = 0; kw < 3; ++kw) {
        #pragma unroll
        for (int j = 0; j < 8; ++j) {
            const int ci = j & 3, jj = j >> 2;
            float v = (ci < 3) ? wqp[ci * 27 + 3 * jj + kw] * LOG2E : 0.f;
            wm[kw][j] = (f16)v;
        }
    }
    f16x8 wg = {};
    if (kq == 0) {
        #pragma unroll
        for (int j = 0; j < 8; ++j) {
            const int ci = j & 3, kw = j >> 2;
            if (ci < 3) wg[j] = (f16)(wc[ci * 27 + 24 + kw] * LOG2E);
        }
    } else if (kq == 1) {
        #pragma unroll
        for (int j = 0; j < 3; ++j) wg[j] = (f16)(wc[j * 27 + 26] * LOG2E);
    }
    const float4 braw = *(const float4*)(bias + kq * 4);
    float4 bv;
    bv.x = braw.x * LOG2E; bv.y = braw.y * LOG2E;
    bv.z = braw.z * LOG2E; bv.w = braw.w * LOG2E;

    // ---- Stage x[b,:,d0..d0+5,0..29,0..31] -> cin-interleaved f16 LDS ----
    for (int i = tid; i < 1440; i += 512) {              // 6 dd * 30 hh * 8 wq
        int wqd = i & 7;
        int r   = i >> 3;
        int hh  = r % 30;
        int dd  = r / 30;
        const float* px = x + ((size_t)b * 48 + (d0 + dd)) * 1024 + hh * 32 + wqd * 4;
        float4 a0 = *(const float4*)(px);
        float4 a1 = *(const float4*)(px + 16384);
        float4 a2 = *(const float4*)(px + 32768);
        f16x8 p0, p1;
        p0[0] = (f16)a0.x; p0[1] = (f16)a1.x; p0[2] = (f16)a2.x; p0[3] = (f16)0.f;
        p0[4] = (f16)a0.y; p0[5] = (f16)a1.y; p0[6] = (f16)a2.y; p0[7] = (f16)0.f;
        p1[0] = (f16)a0.z; p1[1] = (f16)a1.z; p1[2] = (f16)a2.z; p1[3] = (f16)0.f;
        p1[4] = (f16)a0.w; p1[5] = (f16)a1.w; p1[6] = (f16)a2.w; p1[7] = (f16)0.f;
        f16* dst = xs + ((dd * 30 + hh) * 36 + wqd * 4) * 4;
        *(f16x8*)(dst)     = p0;
        *(f16x8*)(dst + 8) = p1;
    }

    // per-lane B-read invariants
    const int g0   = kq * 2;
    const int off1 = (g0 / 3) * PLANEU + (g0 % 3) * ROWU;
    const int off2 = ((g0 + 1) / 3) * PLANEU + ((g0 + 1) % 3) * ROWU;
    const int hl = col >> 2, wl = col & 3;
    const int spat  = hl * ROWU + wl * 4;
    const int g8sel = (kq == 0) ? 0 : 8;

    __syncthreads();   // the only barrier

    for (int c = wave; c < 49; c += 8) {    // cell = ch*7 + pw, ~6 per wave
        const int ch = c / 7;
        const int pw = c - ch * 7;
        const f16* base = xs + ch * 4 * ROWU + pw * 16 + spat;
        const f16* a1 = base + off1;
        const f16* a2 = base + off2;
        const f16* a3 = base + G8OFF + g8sel;

        // ---- 32 B-fragment b64 loads (imm offsets off 3 base addrs) ----
        f16x4 Bv[4][8];
        #pragma unroll
        for (int d = 0; d < 4; ++d) {
            const int dp = d * PLANEU;
            Bv[d][0] = *(const f16x4*)(a1 + dp);
            Bv[d][1] = *(const f16x4*)(a2 + dp);
            Bv[d][2] = *(const f16x4*)(a1 + dp + 4);
            Bv[d][3] = *(const f16x4*)(a2 + dp + 4);
            Bv[d][4] = *(const f16x4*)(a1 + dp + 8);
            Bv[d][5] = *(const f16x4*)(a2 + dp + 8);
            Bv[d][6] = *(const f16x4*)(a3 + dp);
            Bv[d][7] = *(const f16x4*)(a3 + dp + 4);
        }

        // ---- 16 MFMAs: 4 independent chains of 4 ----
        f32x4 acc[4];
        #pragma unroll
        for (int d = 0; d < 4; ++d) {
            f32x4 a_ = {0.f, 0.f, 0.f, 0.f};
            a_ = MFMA16(wm[0], SV8(Bv[d][0], Bv[d][1]), a_);
            a_ = MFMA16(wm[1], SV8(Bv[d][2], Bv[d][3]), a_);
            a_ = MFMA16(wm[2], SV8(Bv[d][4], Bv[d][5]), a_);
            a_ = MFMA16(wg,    SV8(Bv[d][6], Bv[d][7]), a_);
            acc[d] = a_;
        }

        // ---- batched softmax (exp2; weights prescaled) ----
        float ev[4][4], s[4];
        #pragma unroll
        for (int d = 0; d < 4; ++d) {
            float y0 = acc[d][0] + bv.x, y1 = acc[d][1] + bv.y;
            float y2 = acc[d][2] + bv.z, y3 = acc[d][3] + bv.w;
            ev[d][0] = __builtin_amdgcn_exp2f(y0);
            ev[d][1] = __builtin_amdgcn_exp2f(y1);
            ev[d][2] = __builtin_amdgcn_exp2f(y2);
            ev[d][3] = __builtin_amdgcn_exp2f(y3);
            s[d] = (ev[d][0] + ev[d][1]) + (ev[d][2] + ev[d][3]);
        }
        #pragma unroll
        for (int d = 0; d < 4; ++d) s[d] += __shfl_xor(s[d], 16);
        #pragma unroll
        for (int d = 0; d < 4; ++d) s[d] += __shfl_xor(s[d], 32);

        f32x4 pm = {0.f, 0.f, 0.f, 0.f};
        #pragma unroll
        for (int d = 0; d < 4; ++d) {
            float iv = __builtin_amdgcn_rcpf(s[d]);
            pm[0] = fmaxf(pm[0], ev[d][0] * iv);
            pm[1] = fmaxf(pm[1], ev[d][1] * iv);
            pm[2] = fmaxf(pm[2], ev[d][2] * iv);
            pm[3] = fmaxf(pm[3], ev[d][3] * iv);
        }

        // ---- pool over the 16 cell positions on the VALU pipe ----
        #pragma unroll
        for (int r = 0; r < 4; ++r) {
            float v = pm[r];
            DPPMAX(v, 0x128);   // row_ror:8
            DPPMAX(v, 0x124);   // row_ror:4
            DPPMAX(v, 0x122);   // row_ror:2
            DPPMAX(v, 0x121);   // row_ror:1
            pm[r] = v;
        }

        if (col == 0) {
            float* po = out + ((size_t)b * COUT + kq * 4) * 147 + pd * 49 + c;
            po[0]   = pm[0];
            po[147] = pm[1];
            po[294] = pm[2];
            po[441] = pm[3];
        }
    }
}

extern "C" void kernel_launch(void* const* d_in, const int* in_sizes, int n_in,
                              void* d_out, int out_size, void* d_ws, size_t ws_size,
                              hipStream_t stream) {
    const float* x    = (const float*)d_in[0];
    const float* W    = (const float*)d_in[1];
    const float* bias = (const float*)d_in[2];
    float* out = (float*)d_out;

    conv_sm_pool_mfma<<<BATCH * 3, 512, 0, stream>>>(x, W, bias, out);
}

// Round 11
// 30.177 us; speedup vs baseline: 1.2889x; 1.0078x over previous
//
#include <hip/hip_runtime.h>
#include <math.h>

#define BATCH 256
#define CIN   3
#define COUT  16
#define DI    16
#define HI    32
#define WI    32

typedef _Float16 f16;
typedef f16   f16x4 __attribute__((ext_vector_type(4)));
typedef f16   f16x8 __attribute__((ext_vector_type(8)));
typedef float f32x4 __attribute__((ext_vector_type(4)));

#define LOG2E 1.44269504088896340736f

// LDS slab (f16 units): xs[dd][hh][w][ci], ci stride 1 (3 cin + zero pad),
// w stride 4, row stride ROWU=144 f16 (288B), plane stride PLANEU=4320.
// 288B ≡ 32 mod 128 -> 16-col lane group covers all 32 banks; kq-group
// offsets {0,64,96,0} mod 128 -> <=2-way aliasing (free). [R5: 737K conflicts]
#define ROWU   144
#define PLANEU 4320
#define XS_N   (6 * PLANEU)              // 51840 B -> 3 WG/CU (24 waves/CU @512thr)
#define G8OFF  (2 * PLANEU + 2 * ROWU)   // (kd=2,kh=2) row offset

#define SV8(a, b) __builtin_shufflevector(a, b, 0, 1, 2, 3, 4, 5, 6, 7)
#define MFMA16(A, B, C) __builtin_amdgcn_mfma_f32_16x16x32_f16(A, B, C, 0, 0, 0)

// VALU-pipe max-reduce over the 16-lane col group (DPP row_ror). Exact for max.
#define DPPMAX(v, ctrl) do {                                                  \
    int t_ = __builtin_amdgcn_update_dpp(                                     \
        0, __builtin_bit_cast(int, v), (ctrl), 0xF, 0xF, false);              \
    v = fmaxf(v, __builtin_bit_cast(float, t_));                              \
} while (0)

// ---------------------------------------------------------------------------
// Fused conv3d + bias + channel-softmax + 4^3 maxpool.
// One 512-thread WG (8 waves) per (b,pd); 768 WGs = 3 WG/CU, whole grid
// resident, ONE barrier. Each wave owns complete pool cells (~6 each).
// R5's conflict-free LDS layout + exp2-prescaled weights + DPP pool.
// ---------------------------------------------------------------------------
__global__ __launch_bounds__(512, 6) void conv_sm_pool_mfma(
    const float* __restrict__ x, const float* __restrict__ W,
    const float* __restrict__ bias, float* __restrict__ out)
{
    __shared__ __align__(16) f16 xs[XS_N];

    const int tid  = threadIdx.x;
    const int lane = tid & 63;
    const int wave = tid >> 6;           // 0..7
    const int b    = blockIdx.x / 3;
    const int pd   = blockIdx.x % 3;
    const int d0   = pd * 4;

    const int col = lane & 15;     // MFMA column = position in cell (hl*4+wl)
    const int kq  = lane >> 4;     // K-slot group

    // ---- W gather -> A-fragments, PRE-SCALED by log2e (exp -> exp2) ----
    // k = g*4 + ci, g = kd*3+kh; this lane holds groups 2kq, 2kq+1.
    const float* wc  = W + col * 81;
    const float* wqp = wc + kq * 6;
    f16x8 wm[3];
    #pragma unroll
    for (int kw = 0; kw < 3; ++kw) {
        #pragma unroll
        for (int j = 0; j < 8; ++j) {
            const int ci = j & 3, jj = j >> 2;
            float v = (ci < 3) ? wqp[ci * 27 + 3 * jj + kw] * LOG2E : 0.f;
            wm[kw][j] = (f16)v;
        }
    }
    f16x8 wg = {};
    if (kq == 0) {
        #pragma unroll
        for (int j = 0; j < 8; ++j) {
            const int ci = j & 3, kw = j >> 2;
            if (ci < 3) wg[j] = (f16)(wc[ci * 27 + 24 + kw] * LOG2E);
        }
    } else if (kq == 1) {
        #pragma unroll
        for (int j = 0; j < 3; ++j) wg[j] = (f16)(wc[j * 27 + 26] * LOG2E);
    }
    const float4 braw = *(const float4*)(bias + kq * 4);
    float4 bv;
    bv.x = braw.x * LOG2E; bv.y = braw.y * LOG2E;
    bv.z = braw.z * LOG2E; bv.w = braw.w * LOG2E;

    // ---- Stage x[b,:,d0..d0+5,0..29,0..31] -> cin-interleaved f16 LDS ----
    for (int i = tid; i < 1440; i += 512) {              // 6 dd * 30 hh * 8 wq
        int wqd = i & 7;
        int r   = i >> 3;
        int hh  = r % 30;
        int dd  = r / 30;
        const float* px = x + ((size_t)b * 48 + (d0 + dd)) * 1024 + hh * 32 + wqd * 4;
        float4 a0 = *(const float4*)(px);
        float4 a1 = *(const float4*)(px + 16384);
        float4 a2 = *(const float4*)(px + 32768);
        f16x8 p0, p1;
        p0[0] = (f16)a0.x; p0[1] = (f16)a1.x; p0[2] = (f16)a2.x; p0[3] = (f16)0.f;
        p0[4] = (f16)a0.y; p0[5] = (f16)a1.y; p0[6] = (f16)a2.y; p0[7] = (f16)0.f;
        p1[0] = (f16)a0.z; p1[1] = (f16)a1.z; p1[2] = (f16)a2.z; p1[3] = (f16)0.f;
        p1[4] = (f16)a0.w; p1[5] = (f16)a1.w; p1[6] = (f16)a2.w; p1[7] = (f16)0.f;
        f16* dst = xs + ((dd * 30 + hh) * 36 + wqd * 4) * 4;
        *(f16x8*)(dst)     = p0;
        *(f16x8*)(dst + 8) = p1;
    }

    // per-lane B-read invariants
    const int g0   = kq * 2;
    const int off1 = (g0 / 3) * PLANEU + (g0 % 3) * ROWU;
    const int off2 = ((g0 + 1) / 3) * PLANEU + ((g0 + 1) % 3) * ROWU;
    const int hl = col >> 2, wl = col & 3;
    const int spat  = hl * ROWU + wl * 4;
    const int g8sel = (kq == 0) ? 0 : 8;

    __syncthreads();   // the only barrier

    for (int c = wave; c < 49; c += 8) {    // cell = ch*7 + pw, ~6 per wave
        const int ch = c / 7;
        const int pw = c - ch * 7;
        const f16* base = xs + ch * 4 * ROWU + pw * 16 + spat;
        const f16* a1 = base + off1;
        const f16* a2 = base + off2;
        const f16* a3 = base + G8OFF + g8sel;

        // ---- 32 B-fragment b64 loads (imm offsets off 3 base addrs) ----
        f16x4 Bv[4][8];
        #pragma unroll
        for (int d = 0; d < 4; ++d) {
            const int dp = d * PLANEU;
            Bv[d][0] = *(const f16x4*)(a1 + dp);
            Bv[d][1] = *(const f16x4*)(a2 + dp);
            Bv[d][2] = *(const f16x4*)(a1 + dp + 4);
            Bv[d][3] = *(const f16x4*)(a2 + dp + 4);
            Bv[d][4] = *(const f16x4*)(a1 + dp + 8);
            Bv[d][5] = *(const f16x4*)(a2 + dp + 8);
            Bv[d][6] = *(const f16x4*)(a3 + dp);
            Bv[d][7] = *(const f16x4*)(a3 + dp + 4);
        }

        // ---- 16 MFMAs: 4 independent chains of 4 ----
        f32x4 acc[4];
        #pragma unroll
        for (int d = 0; d < 4; ++d) {
            f32x4 a_ = {0.f, 0.f, 0.f, 0.f};
            a_ = MFMA16(wm[0], SV8(Bv[d][0], Bv[d][1]), a_);
            a_ = MFMA16(wm[1], SV8(Bv[d][2], Bv[d][3]), a_);
            a_ = MFMA16(wm[2], SV8(Bv[d][4], Bv[d][5]), a_);
            a_ = MFMA16(wg,    SV8(Bv[d][6], Bv[d][7]), a_);
            acc[d] = a_;
        }

        // ---- batched softmax (exp2; weights prescaled) ----
        float ev[4][4], s[4];
        #pragma unroll
        for (int d = 0; d < 4; ++d) {
            float y0 = acc[d][0] + bv.x, y1 = acc[d][1] + bv.y;
            float y2 = acc[d][2] + bv.z, y3 = acc[d][3] + bv.w;
            ev[d][0] = __builtin_amdgcn_exp2f(y0);
            ev[d][1] = __builtin_amdgcn_exp2f(y1);
            ev[d][2] = __builtin_amdgcn_exp2f(y2);
            ev[d][3] = __builtin_amdgcn_exp2f(y3);
            s[d] = (ev[d][0] + ev[d][1]) + (ev[d][2] + ev[d][3]);
        }
        #pragma unroll
        for (int d = 0; d < 4; ++d) s[d] += __shfl_xor(s[d], 16);
        #pragma unroll
        for (int d = 0; d < 4; ++d) s[d] += __shfl_xor(s[d], 32);

        f32x4 pm = {0.f, 0.f, 0.f, 0.f};
        #pragma unroll
        for (int d = 0; d < 4; ++d) {
            float iv = __builtin_amdgcn_rcpf(s[d]);
            pm[0] = fmaxf(pm[0], ev[d][0] * iv);
            pm[1] = fmaxf(pm[1], ev[d][1] * iv);
            pm[2] = fmaxf(pm[2], ev[d][2] * iv);
            pm[3] = fmaxf(pm[3], ev[d][3] * iv);
        }

        // ---- pool over the 16 cell positions on the VALU pipe ----
        #pragma unroll
        for (int r = 0; r < 4; ++r) {
            float v = pm[r];
            DPPMAX(v, 0x128);   // row_ror:8
            DPPMAX(v, 0x124);   // row_ror:4
            DPPMAX(v, 0x122);   // row_ror:2
            DPPMAX(v, 0x121);   // row_ror:1
            pm[r] = v;
        }

        if (col == 0) {
            float* po = out + ((size_t)b * COUT + kq * 4) * 147 + pd * 49 + c;
            po[0]   = pm[0];
            po[147] = pm[1];
            po[294] = pm[2];
            po[441] = pm[3];
        }
    }
}

extern "C" void kernel_launch(void* const* d_in, const int* in_sizes, int n_in,
                              void* d_out, int out_size, void* d_ws, size_t ws_size,
                              hipStream_t stream) {
    const float* x    = (const float*)d_in[0];
    const float* W    = (const float*)d_in[1];
    const float* bias = (const float*)d_in[2];
    float* out = (float*)d_out;

    conv_sm_pool_mfma<<<BATCH * 3, 512, 0, stream>>>(x, W, bias, out);
}